// Round 1
// baseline (1420.474 us; speedup 1.0000x reference)
//
#include <hip/hip_runtime.h>

// RandomMFGL: out[o][g] = (1/4) * sum_n [ (A[n] @ x) @ W[n] + b[n] ]
// A: [4][4096][16384] fp32 = 1.07 GB streamed once -> HBM-bound, floor ~175us.
//
// v2: previous version delivered wave-uniform x via s_load_dwordx16 (16 scalar
// loads/iter, each feeding only 16 FMAs; SGPR file caps prefetch depth at ~5
// -> serialized lgkmcnt stalls ~1.7k cyc/iter -> 760 GB/s). Now the x-chunk
// (32 KB) is staged once per block into LDS and the inner loop reads it with
// wave-UNIFORM ds_read_b128 (hardware broadcast: conflict-free, VGPR-resident,
// compiler pipelines with rolling lgkmcnt). A-path unchanged: lane = one A-row,
// 64 B of its own line per iteration, zero cross-lane duplication, explicit
// 2-stage register double-buffer keeps 8 VMEM loads in flight.
// Split-K=32 partials into ws (deterministic, no atomics), then a coalesced
// tree-reduce + tiny W/b/mean epilogue.

#define N_ENS 4
#define N_OUT 4096
#define N_IN  16384
#define ROWS  (N_ENS * N_OUT)      // 16384 rows (row = n*4096 + o)
#define GSPLIT 32                  // split-K factor
#define ICHUNK (N_IN / GSPLIT)     // 512 i per (row, split)

// ---------------- kernel 1: hp[split][row][f] = sum_{i in chunk} A[row][i] * x[i][f] ----------------
__global__ __launch_bounds__(256, 4) void k_main(const float* __restrict__ A,
                                                 const float* __restrict__ x,
                                                 float* __restrict__ hp) {
    const int split  = blockIdx.x & (GSPLIT - 1);   // 0..31
    const int rowblk = blockIdx.x >> 5;             // 0..63
    const int tid    = threadIdx.x;
    const int row    = rowblk * 256 + tid;          // lane owns this row
    const int i0     = split * ICHUNK;

    __shared__ float xs[ICHUNK * 16];               // 32 KB: x[i0..i0+511][0..15]

    // cooperative coalesced stage of the x-chunk (8 float4 per thread)
    {
        const float4* xg = (const float4*)(x + (size_t)i0 * 16);
        float4* xl = (float4*)xs;
#pragma unroll
        for (int q = 0; q < 8; ++q)
            xl[tid + 256 * q] = xg[tid + 256 * q];
    }
    __syncthreads();

    const float* Ap = A + (size_t)row * N_IN + i0;

    float acc[16];
#pragma unroll
    for (int f = 0; f < 16; ++f) acc[f] = 0.0f;

#define COMPUTE(buf, sbase) do {                                         \
        const float* af_ = (const float*)(buf);                          \
        const float* xp_ = xs + (sbase) * 256;                           \
        _Pragma("unroll")                                                \
        for (int ii = 0; ii < 16; ++ii) {                                \
            const float av_ = af_[ii];                                   \
            _Pragma("unroll")                                            \
            for (int f = 0; f < 16; ++f)                                 \
                acc[f] = fmaf(av_, xp_[ii * 16 + f], acc[f]);            \
        }                                                                \
    } while (0)

    // 2-stage register double-buffer over the A stream: 64 B per stage.
    float4 aA[4], aB[4];
#pragma unroll
    for (int q = 0; q < 4; ++q) aA[q] = ((const float4*)Ap)[q];

    for (int s = 0; s < ICHUNK / 16; s += 2) {      // 32 stages total, 2 per trip
#pragma unroll
        for (int q = 0; q < 4; ++q) aB[q] = ((const float4*)(Ap + (s + 1) * 16))[q];
        COMPUTE(aA, s);
        if (s + 2 < ICHUNK / 16) {
#pragma unroll
            for (int q = 0; q < 4; ++q) aA[q] = ((const float4*)(Ap + (s + 2) * 16))[q];
        }
        COMPUTE(aB, s + 1);
    }
#undef COMPUTE

    float* outp = hp + ((size_t)split * ROWS + row) * 16;   // 64 B per lane, contiguous
#pragma unroll
    for (int f = 0; f < 16; ++f) outp[f] = acc[f];
}

// ---------------- kernel 2: h[row][f] = sum_split hp[split][row][f] (float4-vectorized) ----------------
__global__ __launch_bounds__(256) void k_hsum(const float4* __restrict__ hp,
                                              float4* __restrict__ h) {
    int t = blockIdx.x * 256 + threadIdx.x;   // 0 .. 65535 float4s
    float4 s; s.x = 0.f; s.y = 0.f; s.z = 0.f; s.w = 0.f;
#pragma unroll
    for (int sp = 0; sp < GSPLIT; ++sp) {
        float4 v = hp[(size_t)sp * (ROWS * 4) + t];
        s.x += v.x; s.y += v.y; s.z += v.z; s.w += v.w;
    }
    h[t] = s;
}

// ---------------- kernel 3: out[o][g] = 0.25 * sum_n (sum_f h[n][o][f]*W[n][f][g] + b[n][g]) ----------------
__global__ __launch_bounds__(256) void k_out(const float* __restrict__ h,
                                             const float* __restrict__ Ws,
                                             const float* __restrict__ bs,
                                             float* __restrict__ out) {
    __shared__ float Wsm[N_ENS * 16 * 16];
    __shared__ float bsm[N_ENS * 16];
    int tid = threadIdx.x;
#pragma unroll
    for (int r = 0; r < 4; ++r) Wsm[tid + 256 * r] = Ws[tid + 256 * r];
    if (tid < 64) bsm[tid] = bs[tid];
    __syncthreads();

    int idx = blockIdx.x * 256 + tid;   // 0..65535
    int o = idx >> 4;
    int gg = idx & 15;
    float s = 0.0f;
#pragma unroll
    for (int n = 0; n < N_ENS; ++n) {
        const float* hr = h + ((size_t)(n * N_OUT + o) << 4);
        float t = 0.0f;
#pragma unroll
        for (int f = 0; f < 16; ++f)
            t = fmaf(hr[f], Wsm[n * 256 + f * 16 + gg], t);
        s += t + bsm[n * 16 + gg];
    }
    out[idx] = 0.25f * s;
}

extern "C" void kernel_launch(void* const* d_in, const int* in_sizes, int n_in,
                              void* d_out, int out_size, void* d_ws, size_t ws_size,
                              hipStream_t stream) {
    const float* x  = (const float*)d_in[0];   // [1, 16384, 16]
    const float* As = (const float*)d_in[1];   // [4, 4096, 16384]
    const float* Ws = (const float*)d_in[2];   // [4, 16, 16]
    const float* bs = (const float*)d_in[3];   // [4, 16]
    float* out = (float*)d_out;                // [1, 4096, 16]

    float* hp = (float*)d_ws;                                     // 32 MB: [32][16384][16]
    float* h  = (float*)((char*)d_ws + (size_t)32 * 1024 * 1024); // 1 MB: [16384][16]

    // hp/h are fully overwritten every call -> no memset needed despite 0xAA poison.
    k_main<<<64 * GSPLIT, 256, 0, stream>>>(As, x, hp);
    k_hsum<<<(ROWS * 16 / 4) / 256, 256, 0, stream>>>((const float4*)hp, (float4*)h);
    k_out<<<(N_OUT * 16) / 256, 256, 0, stream>>>(h, Ws, bs, out);
}